// Round 4
// baseline (150.161 us; speedup 1.0000x reference)
//
#include <hip/hip_runtime.h>

#define K 32
#define NB 8
#define S 16          // index-ordered src chunks per dst-group (parallelism split)

// d_ws layout (ints only; bounds-through-ws pattern proven in R2):
//   [0, 64)                 int bounds[NB+1]
//   [CNT_OFF, +n*S*4)       int cnt[d*S + s]   : per-(dst,chunk) neighbor count (<=K)
//   [SUB_OFF, +n*S*K*4)     int sub[(d*S+s)*K] : per-(dst,chunk) first-K src indices
#define CNT_OFF  4096
#define SUB_OFF  (4096 + (1 << 20))

__global__ void bounds_kernel(const int* __restrict__ batch_src, int n_src,
                              int* __restrict__ bounds) {
    const int b = threadIdx.x;
    if (b > NB) return;
    int lo = 0, hi = n_src;
    while (lo < hi) {
        int mid = (lo + hi) >> 1;
        if (batch_src[mid] < b) lo = mid + 1; else hi = mid;
    }
    bounds[b] = lo;
}

// Phase 1: wave = (dst-group g, chunk s). 64 dsts per wave (one per lane,
// same batch since batch_dst is sorted; straddle waves handled by per-lane
// index windows). Iterate the chunk's src points; each step broadcasts one
// src to all lanes (same-address loads); lanes append hits to private lists.
__global__ __launch_bounds__(256) void scan_kernel(
    const float* __restrict__ src_xyz,
    const float* __restrict__ dst_xyz, const int* __restrict__ batch_dst,
    const int* __restrict__ bounds, int n_dst,
    int* __restrict__ cnt, int* __restrict__ sub)
{
    const int tid  = blockIdx.x * blockDim.x + threadIdx.x;
    const int wave = tid >> 6, lane = tid & 63;
    const int g = wave / S, s = wave % S;
    const int d  = g * 64 + lane;
    const int dc = d < n_dst ? d : n_dst - 1;
    const bool live = (d < n_dst);

    // dst point + |dst|^2, reference-exact fp32 (left-to-right, no FMA).
    const float xd = dst_xyz[3 * dc + 0];
    const float yd = dst_xyz[3 * dc + 1];
    const float zd = dst_xyz[3 * dc + 2];
    const float d2 = __fadd_rn(__fadd_rn(__fmul_rn(xd, xd), __fmul_rn(yd, yd)),
                               __fmul_rn(zd, zd));
    const int b = batch_dst[dc];
    const int my_lo = bounds[b];        // this lane's same-batch src window
    const int my_hi = bounds[b + 1];

    // Wave-shared scan range = union of lane windows (lanes sorted by batch,
    // so lane0 has min start, lane63 max end; union is contiguous).
    const int lo_w = __shfl(my_lo, 0);
    const int hi_w = __shfl(my_hi, 63);
    const int L    = (hi_w - lo_w + S - 1) / S;
    const int c_lo = lo_w + s * L;
    const int c_hi = min(c_lo + L, hi_w);

    int count = 0;
    const long long base = ((long long)d * S + s) * K;

#pragma unroll 4
    for (int j = c_lo; j < c_hi; ++j) {
        // one src point, broadcast to the whole wave (same-address loads)
        const float xs = src_xyz[3 * j + 0];
        const float ys = src_xyz[3 * j + 1];
        const float zs = src_xyz[3 * j + 2];
        const float s2 = __fadd_rn(
            __fadd_rn(__fmul_rn(xs, xs), __fmul_rn(ys, ys)),
            __fmul_rn(zs, zs));
        const float cross = __fadd_rn(
            __fadd_rn(__fmul_rn(xd, xs), __fmul_rn(yd, ys)),
            __fmul_rn(zd, zs));
        const float dist2 = __fsub_rn(__fadd_rn(d2, s2),
                                      __fmul_rn(2.0f, cross));
        // 0.04f == f32(R*R) exactly as the jax reference compares it
        const bool valid = live && (dist2 <= 0.04f) &&
                           (j >= my_lo) && (j < my_hi);
        if (valid && count < K) {
            sub[base + count] = j;
            ++count;
        }
    }
    if (live) cnt[d * S + s] = count;
}

// Phase 2: chunks are index-ordered, so the final first-K list is the
// concatenation of sublists in chunk order, truncated to K. 2 dsts per wave;
// lane k in [0,32) fills output slot k of its dst via a register prefix scan
// over the 16 counts + one gather.
__global__ __launch_bounds__(256) void merge_kernel(
    const int* __restrict__ cnt, const int* __restrict__ sub,
    int n_dst, int* __restrict__ out)
{
    const int tid  = blockIdx.x * blockDim.x + threadIdx.x;
    const int wave = tid >> 6, lane = tid & 63;
    const int d = wave * 2 + (lane >> 5);
    const int k = lane & 31;
    if (d >= n_dst) return;

    const int4* cp = (const int4*)(cnt + (size_t)d * S);
    int cs[S];
#pragma unroll
    for (int q = 0; q < S / 4; ++q) {
        const int4 a = cp[q];
        cs[4 * q + 0] = a.x; cs[4 * q + 1] = a.y;
        cs[4 * q + 2] = a.z; cs[4 * q + 3] = a.w;
    }
    int pref = 0, sel_s = -1, sel_off = 0;
#pragma unroll
    for (int q = 0; q < S; ++q) {
        const int off = k - pref;
        if (off >= 0 && off < cs[q]) { sel_s = q; sel_off = off; }
        pref += cs[q];
    }
    int val = -1;
    if (sel_s >= 0) val = sub[((size_t)d * S + sel_s) * K + sel_off];
    out[(size_t)d * K + k] = val;                                   // edge_src
    out[(size_t)n_dst * K + (size_t)d * K + k] = (val >= 0) ? d : -1; // edge_dst
}

extern "C" void kernel_launch(void* const* d_in, const int* in_sizes, int n_in,
                              void* d_out, int out_size, void* d_ws, size_t ws_size,
                              hipStream_t stream) {
    const float* src_xyz   = (const float*)d_in[0];
    const int*   batch_src = (const int*)d_in[1];
    const float* dst_xyz   = (const float*)d_in[2];
    const int*   batch_dst = (const int*)d_in[3];
    int* out    = (int*)d_out;
    int* bounds = (int*)d_ws;
    int* cnt    = (int*)((char*)d_ws + CNT_OFF);
    int* sub    = (int*)((char*)d_ws + SUB_OFF);

    const int n_src = in_sizes[0] / 3;
    const int n_dst = in_sizes[2] / 3;

    bounds_kernel<<<1, 16, 0, stream>>>(batch_src, n_src, bounds);

    const int G = (n_dst + 63) / 64;
    const int waves1 = G * S;
    scan_kernel<<<(waves1 * 64 + 255) / 256, 256, 0, stream>>>(
        src_xyz, dst_xyz, batch_dst, bounds, n_dst, cnt, sub);

    const int waves2 = (n_dst + 1) / 2;
    merge_kernel<<<(waves2 * 64 + 255) / 256, 256, 0, stream>>>(
        cnt, sub, n_dst, out);
}

// Round 5
// 94.364 us; speedup vs baseline: 1.5913x; 1.5913x over previous
//
#include <hip/hip_runtime.h>

#define K 32
#define NB 8
#define MAXM 40   // max stored hit-masks per dst (covers batch range <= 2560)

// One-shot: bounds[b] = lower_bound(batch_src, b); bounds[NB] = n_src.
__global__ void bounds_kernel(const int* __restrict__ batch_src, int n_src,
                              int* __restrict__ bounds) {
    const int b = threadIdx.x;
    if (b > NB) return;
    int lo = 0, hi = n_src;
    while (lo < hi) {
        int mid = (lo + hi) >> 1;
        if (batch_src[mid] < b) lo = mid + 1; else hi = mid;
    }
    bounds[b] = lo;
}

// Wave per dst. Scan phase records only ballot masks (scalar-lean inner
// loop: no rank math, no scatter stores). Epilogue converts masks -> the
// first-K src indices with a per-lane k-th-set-bit select.
__global__ __launch_bounds__(256) void radius_kernel(
    const float* __restrict__ src_xyz,
    const float* __restrict__ dst_xyz, const int* __restrict__ batch_dst,
    const int* __restrict__ bounds, int n_dst, int* __restrict__ out)
{
    __shared__ unsigned long long s_mask[4][MAXM];
    __shared__ int                s_base[4][MAXM];

    const int w    = threadIdx.x >> 6;          // wave slot within block
    const int lane = threadIdx.x & 63;
    const int d    = (blockIdx.x * blockDim.x + threadIdx.x) >> 6;
    if (d >= n_dst) return;

    // dst point + |dst|^2, reference-exact fp32 (left-to-right, no FMA).
    const float xd = dst_xyz[3 * d + 0];
    const float yd = dst_xyz[3 * d + 1];
    const float zd = dst_xyz[3 * d + 2];
    const float d2 = __fadd_rn(__fadd_rn(__fmul_rn(xd, xd), __fmul_rn(yd, yd)),
                               __fmul_rn(zd, zd));
    const int b     = batch_dst[d];
    const int start = bounds[b];
    const int end   = bounds[b + 1];

    int count = 0;   // wave-uniform total hits recorded
    int nm    = 0;   // wave-uniform number of stored masks

    for (int j0 = start; j0 < end && count < K; j0 += 64) {
        const int j  = j0 + lane;
        const int jc = j < end ? j : end - 1;     // clamped, always legal
        const float xs = src_xyz[3 * jc + 0];
        const float ys = src_xyz[3 * jc + 1];
        const float zs = src_xyz[3 * jc + 2];
        const float s2 = __fadd_rn(
            __fadd_rn(__fmul_rn(xs, xs), __fmul_rn(ys, ys)),
            __fmul_rn(zs, zs));
        const float cross = __fadd_rn(
            __fadd_rn(__fmul_rn(xd, xs), __fmul_rn(yd, ys)),
            __fmul_rn(zd, zs));
        const float dist2 = __fsub_rn(__fadd_rn(d2, s2),
                                      __fmul_rn(2.0f, cross));
        // 0.04f == f32(R*R) exactly as the jax reference compares (R4-proven)
        const bool valid = (j < end) && (dist2 <= 0.04f);
        const unsigned long long m = __ballot(valid);
        if (m != 0ull && nm < MAXM) {            // wave-uniform branch
            if (lane == 0) { s_mask[w][nm] = m; s_base[w][nm] = j0; }
            count += __popcll(m);
            ++nm;
        }
    }

    // Epilogue: lane k emits output slot k = k-th set bit across stored
    // masks in order (masks are index-ordered; scan stopped right after
    // reaching K, so every stored mask is needed — no early break exists).
    const long long obase = (long long)d * K;
    if (lane < K) {
        int rem = lane;
        unsigned long long x = 0ull;
        int jb = 0;
        bool found = false;
        for (int q = 0; q < nm; ++q) {
            const unsigned long long mq = s_mask[w][q];
            const int c = __popcll(mq);
            const bool here = (!found) && (rem < c);
            if (here) { x = mq; jb = s_base[w][q]; }
            if (!found && !here) rem -= c;
            found = found || here;
        }
        int val = -1;
        if (found) {
            // select the rem-th (0-indexed) set bit of x
            int pos = 0;
            unsigned y;
            int c = __popcll(x & 0xFFFFFFFFull);
            if (rem >= c) { rem -= c; y = (unsigned)(x >> 32); pos = 32; }
            else          { y = (unsigned)x; }
            c = __popc(y & 0xFFFFu); if (rem >= c) { rem -= c; y >>= 16; pos += 16; }
            c = __popc(y & 0xFFu);   if (rem >= c) { rem -= c; y >>= 8;  pos += 8;  }
            c = __popc(y & 0xFu);    if (rem >= c) { rem -= c; y >>= 4;  pos += 4;  }
            c = __popc(y & 0x3u);    if (rem >= c) { rem -= c; y >>= 2;  pos += 2;  }
            c = (int)(y & 1u);       if (rem >= c) { pos += 1; }
            val = jb + pos;
        }
        out[obase + lane] = val;                                    // edge_src
        out[(long long)n_dst * K + obase + lane] = found ? d : -1;  // edge_dst
    }
}

extern "C" void kernel_launch(void* const* d_in, const int* in_sizes, int n_in,
                              void* d_out, int out_size, void* d_ws, size_t ws_size,
                              hipStream_t stream) {
    const float* src_xyz   = (const float*)d_in[0];
    const int*   batch_src = (const int*)d_in[1];
    const float* dst_xyz   = (const float*)d_in[2];
    const int*   batch_dst = (const int*)d_in[3];
    int* out    = (int*)d_out;
    int* bounds = (int*)d_ws;    // NB+1 ints (int-staging across kernels: R2/R4-proven)

    const int n_src = in_sizes[0] / 3;
    const int n_dst = in_sizes[2] / 3;

    bounds_kernel<<<1, 16, 0, stream>>>(batch_src, n_src, bounds);

    const int threads = 256;                          // 4 waves/block
    const int blocks = (n_dst * 64 + threads - 1) / threads;
    radius_kernel<<<blocks, threads, 0, stream>>>(
        src_xyz, dst_xyz, batch_dst, bounds, n_dst, out);
}